// Round 1
// baseline (657.877 us; speedup 1.0000x reference)
//
#include <hip/hip_runtime.h>
#include <cstddef>

// LIF constants (match numpy float64->float32 rounding)
static constexpr float A_MEM  = 0.951229424500714f;    // exp(-1/20)
static constexpr float A_SYN  = 0.8187307530779818f;   // exp(-1/5)
static constexpr float OM_MEM = 0.04877057549928599f;  // 1 - exp(-1/20)

// ---------------- GEMM: C[M,N] = A[M,K] @ W[K,N] + bias[N] ----------------
// BM=BN=64, BK=16, 256 threads, 4x4 per-thread microtile. fp32 (no fp32 MFMA on CDNA4).
__global__ __launch_bounds__(256) void gemm_bias(
    const float* __restrict__ A, const float* __restrict__ W,
    const float* __restrict__ bias, float* __restrict__ C,
    int M, int K, int N)
{
    __shared__ float As[16][64];   // A-tile transposed: As[k][m]
    __shared__ float Ws[16][64];   // W-tile: Ws[k][n]
    const int tid = threadIdx.x;
    const int tx = tid & 15;        // N dir (4 cols each)
    const int ty = tid >> 4;        // M dir (4 rows each)
    const int mBase = blockIdx.y * 64;
    const int nBase = blockIdx.x * 64;

    const int arow = tid >> 2;          // 0..63
    const int acol = (tid & 3) << 2;    // 0,4,8,12
    const int wrow = tid >> 4;          // 0..15
    const int wcol = (tid & 15) << 2;   // 0..60

    float acc[4][4] = {};
    for (int k0 = 0; k0 < K; k0 += 16) {
        float4 av = *(const float4*)(A + (size_t)(mBase + arow) * K + (k0 + acol));
        float4 wv = *(const float4*)(W + (size_t)(k0 + wrow) * N + (nBase + wcol));
        __syncthreads();
        As[acol + 0][arow] = av.x;
        As[acol + 1][arow] = av.y;
        As[acol + 2][arow] = av.z;
        As[acol + 3][arow] = av.w;
        *(float4*)&Ws[wrow][wcol] = wv;
        __syncthreads();
        #pragma unroll
        for (int kk = 0; kk < 16; ++kk) {
            float4 a = *(const float4*)&As[kk][ty << 2];
            float4 b = *(const float4*)&Ws[kk][tx << 2];
            float ar[4] = {a.x, a.y, a.z, a.w};
            float br[4] = {b.x, b.y, b.z, b.w};
            #pragma unroll
            for (int i2 = 0; i2 < 4; ++i2)
                #pragma unroll
                for (int j = 0; j < 4; ++j)
                    acc[i2][j] += ar[i2] * br[j];
        }
    }
    const int cn = nBase + (tx << 2);
    float4 bv = *(const float4*)(bias + cn);
    float bb[4] = {bv.x, bv.y, bv.z, bv.w};
    #pragma unroll
    for (int i2 = 0; i2 < 4; ++i2) {
        const int cm = mBase + (ty << 2) + i2;
        float4 o;
        o.x = acc[i2][0] + bb[0];
        o.y = acc[i2][1] + bb[1];
        o.z = acc[i2][2] + bb[2];
        o.w = acc[i2][3] + bb[3];
        *(float4*)(C + (size_t)cm * N + cn) = o;
    }
}

// ---------------- LIF scan over T per (b,h) ----------------
// out value = 2*spike - sg  (forward value of spikes + stopgrad(spikes - sg))
template<bool POOL>
__global__ __launch_bounds__(256) void lif_scan(
    const float* __restrict__ cur, float* __restrict__ out,
    float* __restrict__ pooled, int T, int H)
{
    const int idx = blockIdx.x * 256 + threadIdx.x;   // b*H + h
    const int b = idx / H;
    const int h = idx - b * H;
    const float* cp = cur + (size_t)b * T * H + h;
    float* op = out ? out + (size_t)b * T * H + h : nullptr;
    float v = 0.f, cin = 0.f, sum = 0.f;
    for (int t = 0; t < T; ++t) {
        float ic = cp[(size_t)t * H];
        cin = A_SYN * cin + ic;
        v = A_MEM * v + OM_MEM * cin;
        float s = (v >= 1.0f) ? 1.0f : 0.0f;
        float xx = 4.0f * (v - 1.0f);
        float ch2 = __expf(xx) + __expf(-xx);     // 2*cosh
        float sg = 4.0f / (2.0f + ch2);           // beta/(2(1+cosh)) with beta=4
        float o = 2.0f * s - sg;
        if (POOL) sum += o;
        else op[(size_t)t * H] = o;
        if (s > 0.f) v = 0.0f;
    }
    if (POOL) pooled[idx] = sum * (1.0f / 128.0f);
}

// ---------------- LayerNorm over last dim (one wave per row) ----------------
template<int H>
__global__ __launch_bounds__(256) void layernorm_k(
    const float* __restrict__ x, const float* __restrict__ scale,
    const float* __restrict__ bias, float* __restrict__ y)
{
    constexpr int VPL = H / 64;   // floats per lane
    const int wave = threadIdx.x >> 6;
    const int lane = threadIdx.x & 63;
    const size_t row = (size_t)blockIdx.x * 4 + wave;
    const float* xp = x + row * H + lane * VPL;
    float vals[VPL];
    #pragma unroll
    for (int j = 0; j < VPL; ++j) vals[j] = xp[j];
    float s = 0.f, ss = 0.f;
    #pragma unroll
    for (int j = 0; j < VPL; ++j) { s += vals[j]; ss += vals[j] * vals[j]; }
    #pragma unroll
    for (int off = 32; off; off >>= 1) {
        s  += __shfl_xor(s, off);
        ss += __shfl_xor(ss, off);
    }
    const float mu  = s * (1.0f / H);
    const float var = ss * (1.0f / H) - mu * mu;
    const float rs  = rsqrtf(var + 1e-6f);
    float* yp = y + row * H + lane * VPL;
    #pragma unroll
    for (int j = 0; j < VPL; ++j)
        yp[j] = (vals[j] - mu) * rs * scale[lane * VPL + j] + bias[lane * VPL + j];
}

// ---------------- head: logits = pooled @ Wc + bc ; mean = mean(pooled) ----------------
__global__ __launch_bounds__(1024) void head_k(
    const float* __restrict__ pooled, const float* __restrict__ Wc,
    const float* __restrict__ bc, float* __restrict__ logits,
    float* __restrict__ meanp)
{
    const int tid = threadIdx.x;
    const int b = tid >> 1, c = tid & 1;
    float accl = 0.f;
    #pragma unroll 8
    for (int k = 0; k < 64; ++k) accl += pooled[b * 64 + k] * Wc[k * 2 + c];
    logits[tid] = accl + bc[c];

    float s = 0.f;
    for (int i2 = tid; i2 < 512 * 64; i2 += 1024) s += pooled[i2];
    #pragma unroll
    for (int off = 32; off; off >>= 1) s += __shfl_xor(s, off);
    __shared__ float red[16];
    const int wave = tid >> 6, lane = tid & 63;
    if (lane == 0) red[wave] = s;
    __syncthreads();
    if (tid == 0) {
        float tot = 0.f;
        #pragma unroll
        for (int w = 0; w < 16; ++w) tot += red[w];
        meanp[0] = tot * (1.0f / 32768.0f);
    }
}

extern "C" void kernel_launch(void* const* d_in, const int* in_sizes, int n_in,
                              void* d_out, int out_size, void* d_ws, size_t ws_size,
                              hipStream_t stream) {
    const float* x    = (const float*)d_in[0];   // [512,128,512]
    const float* W0   = (const float*)d_in[1];   // [512,256]
    const float* b0   = (const float*)d_in[2];
    const float* ln1s = (const float*)d_in[3];
    const float* ln1b = (const float*)d_in[4];
    const float* W1   = (const float*)d_in[5];   // [256,128]
    const float* b1   = (const float*)d_in[6];
    const float* ln2s = (const float*)d_in[7];
    const float* ln2b = (const float*)d_in[8];
    const float* W2   = (const float*)d_in[9];   // [128,64]
    const float* b2   = (const float*)d_in[10];
    const float* Wc   = (const float*)d_in[11];  // [64,2]
    const float* bc   = (const float*)d_in[12];

    float* out    = (float*)d_out;
    float* logits = out;                 // [512,2]
    float* pooled = out + 1024;          // [512,64]
    float* meanp  = out + 1024 + 32768;  // [1]

    const int B = 512, T = 128, M = B * T;  // 65536
    float* bufA = (float*)d_ws;                       // 65536*256 floats
    float* bufB = bufA + (size_t)M * 256;             // 65536*256 floats

    // Layer 0: GEMM [65536,512]x[512,256] -> scan
    gemm_bias<<<dim3(256 / 64, M / 64), 256, 0, stream>>>(x, W0, b0, bufA, M, 512, 256);
    lif_scan<false><<<(B * 256) / 256, 256, 0, stream>>>(bufA, bufB, nullptr, T, 256);
    // LN1 -> Layer 1 GEMM [65536,256]x[256,128] -> scan
    layernorm_k<256><<<M / 4, 256, 0, stream>>>(bufB, ln1s, ln1b, bufA);
    gemm_bias<<<dim3(128 / 64, M / 64), 256, 0, stream>>>(bufA, W1, b1, bufB, M, 256, 128);
    lif_scan<false><<<(B * 128) / 256, 256, 0, stream>>>(bufB, bufA, nullptr, T, 128);
    // LN2 -> Layer 2 GEMM [65536,128]x[128,64] -> scan (+pool, no x3 materialization)
    layernorm_k<128><<<M / 4, 256, 0, stream>>>(bufA, ln2s, ln2b, bufB);
    gemm_bias<<<dim3(64 / 64, M / 64), 256, 0, stream>>>(bufB, W2, b2, bufA, M, 128, 64);
    lif_scan<true><<<(B * 64) / 256, 256, 0, stream>>>(bufA, nullptr, pooled, T, 64);
    // Head
    head_k<<<1, 1024, 0, stream>>>(pooled, Wc, bc, logits, meanp);
}

// Round 2
// 639.491 us; speedup vs baseline: 1.0288x; 1.0288x over previous
//
#include <hip/hip_runtime.h>
#include <cstddef>

// LIF constants (match numpy float64->float32 rounding)
static constexpr float A_MEM  = 0.951229424500714f;    // exp(-1/20)
static constexpr float A_SYN  = 0.8187307530779818f;   // exp(-1/5)
static constexpr float OM_MEM = 0.04877057549928599f;  // 1 - exp(-1/20)

// One block = one batch row b. Computes cur = A[b] @ W + bias  (A: [T=128, K],
// W: [K,H]), then LIF scan over t per column h (in LDS), then either LayerNorm
// (write y [B*T,H]) or mean-pool over t (write pooled [B,H]).
// LDS: GEMM staging As[BK][128] + Ws[BK][H]; epilogue buf[T][H] ALIASES it.
template<int NT, int K, int H, bool LN, bool POOL>
__global__ __launch_bounds__(NT) void layer_fused(
    const float* __restrict__ A, const float* __restrict__ W,
    const float* __restrict__ bias,
    const float* __restrict__ lns, const float* __restrict__ lnb,
    float* __restrict__ out)
{
  constexpr int T = 128;
  constexpr int BK = 16;
  constexpr int TXB = (NT == 512) ? 5 : 4;
  constexpr int NTX = 1 << TXB;            // lanes across N: 32 or 16
  constexpr int NJ  = H / NTX;             // cols per thread (8 or 4)
  constexpr int S   = K / BK;              // K-steps
  constexpr int APT = (BK * 128 / 4) / NT; // float4 per thread for A (1 or 2)
  constexpr int WPT = (BK * H / 4) / NT < 1 ? 1 : (BK * H / 4) / NT;
  extern __shared__ __align__(16) float smem[];
  float* As  = smem;              // [BK][128] (k-major, transposed)
  float* Ws  = smem + BK * 128;   // [BK][H]
  float* buf = smem;              // [T][H] — aliases staging after GEMM

  const int b   = blockIdx.x;
  const int tid = threadIdx.x;
  const int tx  = tid & (NTX - 1);
  const int ty  = tid >> TXB;     // 0..15 (8 rows each)
  const float* Ab = A + (size_t)b * T * K;

  float acc[8][NJ];
  #pragma unroll
  for (int i = 0; i < 8; ++i)
    #pragma unroll
    for (int j = 0; j < NJ; ++j) acc[i][j] = 0.f;

  float4 aR[APT], wR[WPT];
  auto load_tile = [&](int k0) {
    #pragma unroll
    for (int p = 0; p < APT; ++p) {
      int f4 = tid + p * NT;
      int r  = f4 >> 2;
      int c4 = (f4 & 3) << 2;
      aR[p] = *(const float4*)(Ab + (size_t)r * K + k0 + c4);
    }
    #pragma unroll
    for (int p = 0; p < WPT; ++p) {
      int f4 = tid + p * NT;
      int k  = f4 / (H / 4);
      int c4 = (f4 % (H / 4)) << 2;
      wR[p] = *(const float4*)(W + (size_t)(k0 + k) * H + c4);
    }
  };

  load_tile(0);
  for (int s = 0; s < S; ++s) {
    __syncthreads();   // previous compute done reading LDS
    #pragma unroll
    for (int p = 0; p < APT; ++p) {
      int f4 = tid + p * NT;
      int r  = f4 >> 2;
      int c4 = (f4 & 3) << 2;
      As[(c4 + 0) * 128 + r] = aR[p].x;
      As[(c4 + 1) * 128 + r] = aR[p].y;
      As[(c4 + 2) * 128 + r] = aR[p].z;
      As[(c4 + 3) * 128 + r] = aR[p].w;
    }
    #pragma unroll
    for (int p = 0; p < WPT; ++p) {
      int f4 = tid + p * NT;
      int k  = f4 / (H / 4);
      int c4 = (f4 % (H / 4)) << 2;
      *(float4*)(Ws + k * H + c4) = wR[p];
    }
    __syncthreads();
    if (s + 1 < S) load_tile((s + 1) * BK);   // prefetch hides under compute
    #pragma unroll
    for (int kk = 0; kk < BK; ++kk) {
      float4 a0 = *(const float4*)(As + kk * 128 + ty * 8);
      float4 a1 = *(const float4*)(As + kk * 128 + ty * 8 + 4);
      float av[8] = {a0.x, a0.y, a0.z, a0.w, a1.x, a1.y, a1.z, a1.w};
      float bv[NJ];
      #pragma unroll
      for (int j = 0; j < NJ; ++j) bv[j] = Ws[kk * H + j * NTX + tx];
      #pragma unroll
      for (int i = 0; i < 8; ++i)
        #pragma unroll
        for (int j = 0; j < NJ; ++j)
          acc[i][j] += av[i] * bv[j];
    }
  }

  __syncthreads();   // done with As/Ws; buf may overwrite them
  {
    float bb[NJ];
    #pragma unroll
    for (int j = 0; j < NJ; ++j) bb[j] = bias[j * NTX + tx];
    #pragma unroll
    for (int i = 0; i < 8; ++i) {
      int row = ty * 8 + i;
      #pragma unroll
      for (int j = 0; j < NJ; ++j)
        buf[row * H + j * NTX + tx] = acc[i][j] + bb[j];
    }
  }
  __syncthreads();

  // LIF scan: thread h walks t. Reads/writes LDS column h (conflict-free).
  if (tid < H) {
    float v = 0.f, cin = 0.f, sum = 0.f;
    for (int t = 0; t < T; ++t) {
      float ic = buf[t * H + tid];
      cin = A_SYN * cin + ic;
      v = A_MEM * v + OM_MEM * cin;
      bool sp = (v >= 1.0f);
      float xx = 4.0f * (v - 1.0f);
      float e  = __expf(xx);
      float tp = 1.0f + e;
      float sg = 4.0f * e / (tp * tp);   // == BETA/(2(1+cosh(BETA(v-1))))
      float o  = (sp ? 2.0f : 0.0f) - sg;
      if (POOL) sum += o;
      else buf[t * H + tid] = o;
      v = sp ? 0.0f : v;
    }
    if (POOL) out[(size_t)b * H + tid] = sum * (1.0f / 128.0f);
  }

  if (LN) {
    __syncthreads();
    constexpr int VPL = H / 64;
    constexpr int NW  = NT / 64;
    const int wv   = tid >> 6;
    const int lane = tid & 63;
    float sc[VPL], bi[VPL];
    #pragma unroll
    for (int q = 0; q < VPL; ++q) {
      sc[q] = lns[lane * VPL + q];
      bi[q] = lnb[lane * VPL + q];
    }
    for (int t = wv; t < T; t += NW) {
      float vals[VPL];
      #pragma unroll
      for (int q = 0; q < VPL; ++q) vals[q] = buf[t * H + lane * VPL + q];
      float s1 = 0.f, s2 = 0.f;
      #pragma unroll
      for (int q = 0; q < VPL; ++q) { s1 += vals[q]; s2 += vals[q] * vals[q]; }
      #pragma unroll
      for (int off = 32; off; off >>= 1) {
        s1 += __shfl_xor(s1, off);
        s2 += __shfl_xor(s2, off);
      }
      float mu  = s1 * (1.0f / H);
      float var = s2 * (1.0f / H) - mu * mu;
      float rs  = rsqrtf(var + 1e-6f);
      float* op = out + ((size_t)b * T + t) * H + lane * VPL;
      #pragma unroll
      for (int q = 0; q < VPL; ++q)
        op[q] = (vals[q] - mu) * rs * sc[q] + bi[q];
    }
  }
}

// head: logits = pooled @ Wc + bc ; mean = mean(pooled)
__global__ __launch_bounds__(1024) void head_k(
    const float* __restrict__ pooled, const float* __restrict__ Wc,
    const float* __restrict__ bc, float* __restrict__ logits,
    float* __restrict__ meanp)
{
    const int tid = threadIdx.x;
    const int b = tid >> 1, c = tid & 1;
    float accl = 0.f;
    #pragma unroll 8
    for (int k = 0; k < 64; ++k) accl += pooled[b * 64 + k] * Wc[k * 2 + c];
    logits[tid] = accl + bc[c];

    float s = 0.f;
    for (int i2 = tid; i2 < 512 * 64; i2 += 1024) s += pooled[i2];
    #pragma unroll
    for (int off = 32; off; off >>= 1) s += __shfl_xor(s, off);
    __shared__ float red[16];
    const int wave = tid >> 6, lane = tid & 63;
    if (lane == 0) red[wave] = s;
    __syncthreads();
    if (tid == 0) {
        float tot = 0.f;
        #pragma unroll
        for (int w = 0; w < 16; ++w) tot += red[w];
        meanp[0] = tot * (1.0f / 32768.0f);
    }
}

extern "C" void kernel_launch(void* const* d_in, const int* in_sizes, int n_in,
                              void* d_out, int out_size, void* d_ws, size_t ws_size,
                              hipStream_t stream) {
    const float* x    = (const float*)d_in[0];   // [512,128,512]
    const float* W0   = (const float*)d_in[1];   // [512,256]
    const float* b0   = (const float*)d_in[2];
    const float* ln1s = (const float*)d_in[3];
    const float* ln1b = (const float*)d_in[4];
    const float* W1   = (const float*)d_in[5];   // [256,128]
    const float* b1   = (const float*)d_in[6];
    const float* ln2s = (const float*)d_in[7];
    const float* ln2b = (const float*)d_in[8];
    const float* W2   = (const float*)d_in[9];   // [128,64]
    const float* b2   = (const float*)d_in[10];
    const float* Wc   = (const float*)d_in[11];  // [64,2]
    const float* bc   = (const float*)d_in[12];

    float* out    = (float*)d_out;
    float* logits = out;                 // [512,2]
    float* pooled = out + 1024;          // [512,64]
    float* meanp  = out + 1024 + 32768;  // [1]

    const int B = 512;
    float* y1 = (float*)d_ws;                    // [65536,256]
    float* y2 = y1 + (size_t)65536 * 256;        // [65536,128]

    // Allow >64KB dynamic LDS (no-op if not required on this runtime).
    (void)hipFuncSetAttribute((const void*)&layer_fused<512,512,256,true,false>,
                              hipFuncAttributeMaxDynamicSharedMemorySize, 131072);
    (void)hipFuncSetAttribute((const void*)&layer_fused<256,256,128,true,false>,
                              hipFuncAttributeMaxDynamicSharedMemorySize, 65536);
    (void)hipFuncSetAttribute((const void*)&layer_fused<256,128,64,false,true>,
                              hipFuncAttributeMaxDynamicSharedMemorySize, 32768);

    layer_fused<512,512,256,true,false><<<B, 512, 131072, stream>>>(
        x,  W0, b0, ln1s, ln1b, y1);
    layer_fused<256,256,128,true,false><<<B, 256, 65536, stream>>>(
        y1, W1, b1, ln2s, ln2b, y2);
    layer_fused<256,128,64,false,true><<<B, 256, 32768, stream>>>(
        y2, W2, b2, nullptr, nullptr, pooled);
    head_k<<<1, 1024, 0, stream>>>(pooled, Wc, bc, logits, meanp);
}

// Round 4
// 623.491 us; speedup vs baseline: 1.0552x; 1.0257x over previous
//
#include <hip/hip_runtime.h>
#include <cstddef>

// LIF constants (match numpy float64->float32 rounding)
static constexpr float A_MEM  = 0.951229424500714f;    // exp(-1/20)
static constexpr float A_SYN  = 0.8187307530779818f;   // exp(-1/5)
static constexpr float OM_MEM = 0.04877057549928599f;  // 1 - exp(-1/20)

// ---- fp32 GEMM, BN = full N (A fetched once), optional fused LayerNorm on A ----
// C[M,BN] = LN(A)[M,K] @ W[K,BN] + bias. 256 threads, microtile 8 rows x (2*CJ) cols.
template<int BM, int BN, int K, bool LN>
__global__ __launch_bounds__(256) void gemm_ln(
    const float* __restrict__ A, const float* __restrict__ W,
    const float* __restrict__ bias,
    const float2* __restrict__ stats, const float* __restrict__ lnsc,
    const float* __restrict__ lnbi, float* __restrict__ C)
{
  constexpr int BK   = 16;
  constexpr int S    = K / BK;
  constexpr int PA   = BM + 4;          // pad: transposed-A writes are 2-way max
  constexpr int NTYG = BM / 8;          // row groups (8 or 16)
  constexpr int NTX  = 256 / NTYG;      // threads across N (32 or 16)
  constexpr int CJ   = BN / (NTX * 2);  // float2 col groups per thread
  constexpr int APT  = BM / 64;         // A float4 loads per thread
  constexpr int WPT  = BN / 64;         // W float4 loads per thread

  __shared__ float As[BK][PA];   // transposed: As[k][m]
  __shared__ float Ws[BK][BN];

  const int tid = threadIdx.x;
  const int tx  = tid % NTX;
  const int ty  = tid / NTX;
  const int m0  = blockIdx.x * BM;

  float4 aR[APT], wR[WPT];

  auto load_tile = [&](int k0) {
    #pragma unroll
    for (int p = 0; p < APT; ++p) {
      int idx = tid + p * 256;
      int r = idx >> 2, c4 = (idx & 3) << 2;
      float4 a = *(const float4*)(A + (size_t)(m0 + r) * K + k0 + c4);
      if constexpr (LN) {
        float2 st = stats[m0 + r];       // (mu, rsqrt(var+eps))
        float4 ls = *(const float4*)(lnsc + k0 + c4);
        float4 lb = *(const float4*)(lnbi + k0 + c4);
        a.x = (a.x - st.x) * st.y * ls.x + lb.x;
        a.y = (a.y - st.x) * st.y * ls.y + lb.y;
        a.z = (a.z - st.x) * st.y * ls.z + lb.z;
        a.w = (a.w - st.x) * st.y * ls.w + lb.w;
      }
      aR[p] = a;
    }
    #pragma unroll
    for (int p = 0; p < WPT; ++p) {
      int idx = tid + p * 256;
      int k = idx / (BN / 4), c4 = (idx % (BN / 4)) << 2;
      wR[p] = *(const float4*)(W + (size_t)(k0 + k) * BN + c4);
    }
  };

  auto store_tile = [&]() {
    #pragma unroll
    for (int p = 0; p < APT; ++p) {
      int idx = tid + p * 256;
      int r = idx >> 2, c4 = (idx & 3) << 2;
      As[c4 + 0][r] = aR[p].x;
      As[c4 + 1][r] = aR[p].y;
      As[c4 + 2][r] = aR[p].z;
      As[c4 + 3][r] = aR[p].w;
    }
    #pragma unroll
    for (int p = 0; p < WPT; ++p) {
      int idx = tid + p * 256;
      int k = idx / (BN / 4), c4 = (idx % (BN / 4)) << 2;
      *(float4*)&Ws[k][c4] = wR[p];
    }
  };

  float acc[8][CJ * 2];
  #pragma unroll
  for (int i = 0; i < 8; ++i)
    #pragma unroll
    for (int j = 0; j < CJ * 2; ++j) acc[i][j] = 0.f;

  load_tile(0);
  for (int s = 0; s < S; ++s) {
    __syncthreads();
    store_tile();
    __syncthreads();
    if (s + 1 < S) load_tile((s + 1) * BK);  // prefetch hides under compute
    #pragma unroll
    for (int kk = 0; kk < BK; ++kk) {
      float4 a0 = *(const float4*)&As[kk][ty * 8];
      float4 a1 = *(const float4*)&As[kk][ty * 8 + 4];
      float av[8] = {a0.x, a0.y, a0.z, a0.w, a1.x, a1.y, a1.z, a1.w};
      float2 wv[CJ];
      #pragma unroll
      for (int j = 0; j < CJ; ++j)
        wv[j] = *(const float2*)&Ws[kk][tx * 2 + j * NTX * 2];
      #pragma unroll
      for (int i = 0; i < 8; ++i)
        #pragma unroll
        for (int j = 0; j < CJ; ++j) {
          acc[i][2 * j]     += av[i] * wv[j].x;
          acc[i][2 * j + 1] += av[i] * wv[j].y;
        }
    }
  }

  #pragma unroll
  for (int j = 0; j < CJ; ++j) {
    int col = tx * 2 + j * NTX * 2;
    float2 bb = *(const float2*)(bias + col);
    #pragma unroll
    for (int i = 0; i < 8; ++i) {
      int row = m0 + ty * 8 + i;
      float2 o;
      o.x = acc[i][2 * j]     + bb.x;
      o.y = acc[i][2 * j + 1] + bb.y;
      *(float2*)(C + (size_t)row * BN + col) = o;
    }
  }
}

// ---- LIF scan (in-place) + deterministic per-(b,t) LN stats (mu, rs) ----
template<int H, int BPB>   // BPB batches per 256-thread block
__global__ __launch_bounds__(256) void lif_stats(
    float* __restrict__ cur, float2* __restrict__ stats)
{
  constexpr int T = 128;
  constexpr int WPB = H / 64;   // waves per batch
  const int tid  = threadIdx.x;
  const int bl   = tid / H;
  const int h    = tid % H;
  const size_t b = (size_t)blockIdx.x * BPB + bl;
  float* p = cur + b * T * H + h;
  __shared__ float w1[4][T], w2[4][T];
  const int wv = tid >> 6, lane = tid & 63;
  float v = 0.f, ci = 0.f;
  for (int t0 = 0; t0 < T; t0 += 4) {
    float ic[4];
    #pragma unroll
    for (int u = 0; u < 4; ++u) ic[u] = p[(size_t)(t0 + u) * H];  // 4 loads in flight
    #pragma unroll
    for (int u = 0; u < 4; ++u) {
      ci = A_SYN * ci + ic[u];
      v  = A_MEM * v + OM_MEM * ci;
      bool sp = v >= 1.0f;
      float xx = 4.0f * (v - 1.0f);
      float e  = __expf(xx);
      float tp = 1.0f + e;
      float sg = 4.0f * e / (tp * tp);   // == BETA/(2(1+cosh(BETA(v-1))))
      float o  = (sp ? 2.0f : 0.0f) - sg;
      v = sp ? 0.0f : v;
      ic[u] = o;
      float s1 = o, s2 = o * o;
      #pragma unroll
      for (int off = 1; off < 64; off <<= 1) {
        s1 += __shfl_xor(s1, off);
        s2 += __shfl_xor(s2, off);
      }
      if (lane == 0) { w1[wv][t0 + u] = s1; w2[wv][t0 + u] = s2; }
    }
    #pragma unroll
    for (int u = 0; u < 4; ++u) p[(size_t)(t0 + u) * H] = ic[u];
  }
  __syncthreads();
  if (tid < T * BPB) {
    int t  = tid & (T - 1);
    int bs = tid >> 7;
    float s1 = 0.f, s2 = 0.f;
    #pragma unroll
    for (int w = 0; w < WPB; ++w) {
      s1 += w1[bs * WPB + w][t];
      s2 += w2[bs * WPB + w][t];
    }
    float mu  = s1 * (1.0f / H);
    float var = s2 * (1.0f / H) - mu * mu;
    float rs  = rsqrtf(var + 1e-6f);
    stats[((size_t)blockIdx.x * BPB + bs) * T + t] = make_float2(mu, rs);
  }
}

// ---- layer-2 LIF scan + mean pool (no x3 materialization) ----
__global__ __launch_bounds__(256) void lif_pool(
    const float* __restrict__ cur, float* __restrict__ pooled)
{
  constexpr int T = 128, H = 64;
  int flat = blockIdx.x * 256 + threadIdx.x;   // b*64 + h, 32768 total
  int b = flat >> 6, h = flat & 63;
  const float* p = cur + (size_t)b * T * H + h;
  float v = 0.f, ci = 0.f, sum = 0.f;
  for (int t0 = 0; t0 < T; t0 += 4) {
    float ic[4];
    #pragma unroll
    for (int u = 0; u < 4; ++u) ic[u] = p[(size_t)(t0 + u) * H];
    #pragma unroll
    for (int u = 0; u < 4; ++u) {
      ci = A_SYN * ci + ic[u];
      v  = A_MEM * v + OM_MEM * ci;
      bool sp = v >= 1.0f;
      float xx = 4.0f * (v - 1.0f);
      float e  = __expf(xx);
      float tp = 1.0f + e;
      float sg = 4.0f * e / (tp * tp);
      sum += (sp ? 2.0f : 0.0f) - sg;
      v = sp ? 0.0f : v;
    }
  }
  pooled[flat] = sum * (1.0f / 128.0f);
}

// ---- head: logits = pooled @ Wc + bc ; mean = mean(pooled) ----
__global__ __launch_bounds__(1024) void head_k(
    const float* __restrict__ pooled, const float* __restrict__ Wc,
    const float* __restrict__ bc, float* __restrict__ logits,
    float* __restrict__ meanp)
{
  const int tid = threadIdx.x;
  const int b = tid >> 1, c = tid & 1;
  float accl = 0.f;
  #pragma unroll 8
  for (int k = 0; k < 64; ++k) accl += pooled[b * 64 + k] * Wc[k * 2 + c];
  logits[tid] = accl + bc[c];

  float s = 0.f;
  for (int i2 = tid; i2 < 512 * 64; i2 += 1024) s += pooled[i2];
  #pragma unroll
  for (int off = 32; off; off >>= 1) s += __shfl_xor(s, off);
  __shared__ float red[16];
  const int wave = tid >> 6, lane = tid & 63;
  if (lane == 0) red[wave] = s;
  __syncthreads();
  if (tid == 0) {
    float tot = 0.f;
    #pragma unroll
    for (int w = 0; w < 16; ++w) tot += red[w];
    meanp[0] = tot * (1.0f / 32768.0f);
  }
}

extern "C" void kernel_launch(void* const* d_in, const int* in_sizes, int n_in,
                              void* d_out, int out_size, void* d_ws, size_t ws_size,
                              hipStream_t stream) {
  const float* x    = (const float*)d_in[0];   // [512,128,512]
  const float* W0   = (const float*)d_in[1];   // [512,256]
  const float* b0   = (const float*)d_in[2];
  const float* ln1s = (const float*)d_in[3];
  const float* ln1b = (const float*)d_in[4];
  const float* W1   = (const float*)d_in[5];   // [256,128]
  const float* b1   = (const float*)d_in[6];
  const float* ln2s = (const float*)d_in[7];
  const float* ln2b = (const float*)d_in[8];
  const float* W2   = (const float*)d_in[9];   // [128,64]
  const float* b2   = (const float*)d_in[10];
  const float* Wc   = (const float*)d_in[11];  // [64,2]
  const float* bc   = (const float*)d_in[12];

  float* out    = (float*)d_out;
  float* logits = out;                 // [512,2]
  float* pooled = out + 1024;          // [512,64]
  float* meanp  = out + 1024 + 32768;  // [1]

  char* ws = (char*)d_ws;
  float*  cur0   = (float*)ws;                              // 64 MB [65536,256]
  float*  cur1   = (float*)(ws + (size_t)64 * 1024 * 1024); // 32 MB [65536,128]
  float*  cur2   = (float*)(ws + (size_t)96 * 1024 * 1024); // 16 MB [65536,64]
  float2* stats0 = (float2*)(ws + (size_t)112 * 1024 * 1024);           // 512 KB
  float2* stats1 = (float2*)(ws + (size_t)112 * 1024 * 1024 + 524288);  // 512 KB

  // layer 0: GEMM [65536,512]x[512,256]; scan + stats for LN1
  gemm_ln<64, 256, 512, false><<<1024, 256, 0, stream>>>(
      x, W0, b0, nullptr, nullptr, nullptr, cur0);
  lif_stats<256, 1><<<512, 256, 0, stream>>>(cur0, stats0);
  // layer 1: LN1 fused into staging; scan + stats for LN2
  gemm_ln<64, 128, 256, true><<<1024, 256, 0, stream>>>(
      cur0, W1, b1, stats0, ln1s, ln1b, cur1);
  lif_stats<128, 2><<<256, 256, 0, stream>>>(cur1, stats1);
  // layer 2: LN2 fused; scan + pool (x3 never materialized)
  gemm_ln<128, 64, 128, true><<<512, 256, 0, stream>>>(
      cur1, W2, b2, stats1, ln2s, ln2b, cur2);
  lif_pool<<<128, 256, 0, stream>>>(cur2, pooled);
  // head
  head_k<<<1, 1024, 0, stream>>>(pooled, Wc, bc, logits, meanp);
}